// Round 1
// baseline (890.314 us; speedup 1.0000x reference)
//
#include <hip/hip_runtime.h>
#include <math.h>

#define Bn 128
#define Tn 512
#define Cn 256
#define Hn 64

#define CP 260   // padded LDS stride for x tile (multiple of 4, breaks 32-bank pow2)
#define HP 68    // padded LDS stride for 64-wide tiles

__device__ __forceinline__ void fma4(float4& a, float s, const float4 w) {
    a.x = fmaf(s, w.x, a.x); a.y = fmaf(s, w.y, a.y);
    a.z = fmaf(s, w.z, a.z); a.w = fmaf(s, w.w, a.w);
}

// ---------------------------------------------------------------------------
// QKV projection: x[B*T, C] @ W[C, H] for Wq, Wk, Wv.
// One block = 64 rows, 256 threads. Thread (r = tid/4, g = tid%4) computes
// outputs [row r][h = g*16 .. g*16+15] for each of the 3 matrices.
// ---------------------------------------------------------------------------
__global__ __launch_bounds__(256) void qkv_proj_kernel(
    const float* __restrict__ x,
    const float* __restrict__ Wq, const float* __restrict__ Wk,
    const float* __restrict__ Wv,
    float* __restrict__ q, float* __restrict__ k, float* __restrict__ v)
{
    __shared__ float xs[64][CP];
    const int tid = threadIdx.x;
    const long row0 = (long)blockIdx.x * 64;

    // stage 64 rows x 256 cols (4096 float4, 16 per thread, coalesced)
    const float4* x4 = (const float4*)(x + row0 * Cn);
    #pragma unroll
    for (int i = 0; i < 16; ++i) {
        int idx = tid + i * 256;      // 0..4095
        int r   = idx >> 6;           // 64 float4 per row
        int c4  = idx & 63;
        *(float4*)&xs[r][c4 * 4] = x4[idx];
    }
    __syncthreads();

    const int r = tid >> 2;
    const int g = tid & 3;
    const float* Ws[3]  = {Wq, Wk, Wv};
    float*       outs[3] = {q, k, v};

    #pragma unroll
    for (int m = 0; m < 3; ++m) {
        const float4* W4 = (const float4*)(Ws[m]);   // [256][16] float4 view
        float4 a0 = {0.f,0.f,0.f,0.f}, a1 = a0, a2 = a0, a3 = a0;
        for (int c = 0; c < Cn; ++c) {
            float xv = xs[r][c];
            const float4* wrow = W4 + c * 16 + g * 4;
            fma4(a0, xv, wrow[0]);
            fma4(a1, xv, wrow[1]);
            fma4(a2, xv, wrow[2]);
            fma4(a3, xv, wrow[3]);
        }
        float4* o4 = (float4*)(outs[m] + (row0 + r) * Hn + g * 16);
        o4[0] = a0; o4[1] = a1; o4[2] = a2; o4[3] = a3;
    }
}

// ---------------------------------------------------------------------------
// Flash-style causal attention over q,k,v [B, T, H].
// Block = (q-tile of 64 rows, batch). 256 threads.
// Thread (r = tid/4, g = tid%4):
//   scores  for kc = g + 4*j   (j = 0..15)  -> row softmax via 4-lane shuffles
//   output  for h  = g*16 + j  (j = 0..15)
// ---------------------------------------------------------------------------
__global__ __launch_bounds__(256) void attn_kernel(
    const float* __restrict__ q, const float* __restrict__ k,
    const float* __restrict__ v, float* __restrict__ out)
{
    __shared__ float qs[64][HP], ks[64][HP], vs[64][HP], ps[64][HP];
    const int tid = threadIdx.x;
    const int qt  = blockIdx.x;    // 0..7
    const int b   = blockIdx.y;    // 0..127
    const long base  = (long)b * Tn * Hn;
    const long qrow0 = (long)qt * 64;

    // stage Q tile (64x64 floats = 1024 float4)
    {
        const float4* q4 = (const float4*)(q + base + qrow0 * Hn);
        #pragma unroll
        for (int i = 0; i < 4; ++i) {
            int idx = tid + i * 256;    // 0..1023
            int rr  = idx >> 4;         // 16 float4 per row
            int c4  = idx & 15;
            *(float4*)&qs[rr][c4 * 4] = q4[idx];
        }
    }

    const int r = tid >> 2;
    const int g = tid & 3;
    float o[16];
    #pragma unroll
    for (int j = 0; j < 16; ++j) o[j] = 0.f;
    float mrow = -INFINITY, lrow = 0.f;

    for (int kt = 0; kt <= qt; ++kt) {
        __syncthreads();   // previous iter done with ks/vs
        {
            const float4* k4 = (const float4*)(k + base + (long)kt * 64 * Hn);
            const float4* v4 = (const float4*)(v + base + (long)kt * 64 * Hn);
            #pragma unroll
            for (int i = 0; i < 4; ++i) {
                int idx = tid + i * 256;
                int rr  = idx >> 4;
                int c4  = idx & 15;
                *(float4*)&ks[rr][c4 * 4] = k4[idx];
                *(float4*)&vs[rr][c4 * 4] = v4[idx];
            }
        }
        __syncthreads();

        // ---- scores S[r][kc], kc = g + 4j ----
        float sc[16];
        #pragma unroll
        for (int j = 0; j < 16; ++j) sc[j] = 0.f;
        for (int c4 = 0; c4 < 16; ++c4) {
            float4 qv = *(const float4*)&qs[r][c4 * 4];
            #pragma unroll
            for (int j = 0; j < 16; ++j) {
                float4 kv = *(const float4*)&ks[g + 4 * j][c4 * 4];
                sc[j] = fmaf(qv.x, kv.x, sc[j]);
                sc[j] = fmaf(qv.y, kv.y, sc[j]);
                sc[j] = fmaf(qv.z, kv.z, sc[j]);
                sc[j] = fmaf(qv.w, kv.w, sc[j]);
            }
        }

        // scale + causal mask (diag tile only)
        if (kt == qt) {
            #pragma unroll
            for (int j = 0; j < 16; ++j) {
                int kc = g + 4 * j;
                sc[j] = (kc <= r) ? sc[j] * 0.125f : -INFINITY;
            }
        } else {
            #pragma unroll
            for (int j = 0; j < 16; ++j) sc[j] *= 0.125f;
        }

        // ---- online softmax (row reduction over 4 lanes) ----
        float sMax = -INFINITY;
        #pragma unroll
        for (int j = 0; j < 16; ++j) sMax = fmaxf(sMax, sc[j]);
        sMax = fmaxf(sMax, __shfl_xor(sMax, 1));
        sMax = fmaxf(sMax, __shfl_xor(sMax, 2));
        float mNew  = fmaxf(mrow, sMax);
        float scale = __expf(mrow - mNew);   // first tile: exp(-inf) = 0

        float psum = 0.f;
        #pragma unroll
        for (int j = 0; j < 16; ++j) {
            float p = __expf(sc[j] - mNew);  // masked: exp(-inf) = 0
            ps[r][g + 4 * j] = p;
            psum += p;
        }
        psum += __shfl_xor(psum, 1);
        psum += __shfl_xor(psum, 2);
        lrow = lrow * scale + psum;
        mrow = mNew;
        #pragma unroll
        for (int j = 0; j < 16; ++j) o[j] *= scale;

        // ---- PV: o[h=g*16+j] += sum_s P[r][s] * V[s][h] ----
        // ps row written by this row's own 4 lanes (same wave) -> no barrier
        for (int s = 0; s < 64; ++s) {
            float p = ps[r][s];
            #pragma unroll
            for (int j4 = 0; j4 < 4; ++j4) {
                float4 vv = *(const float4*)&vs[s][g * 16 + j4 * 4];
                o[j4*4+0] = fmaf(p, vv.x, o[j4*4+0]);
                o[j4*4+1] = fmaf(p, vv.y, o[j4*4+1]);
                o[j4*4+2] = fmaf(p, vv.z, o[j4*4+2]);
                o[j4*4+3] = fmaf(p, vv.w, o[j4*4+3]);
            }
        }
    }

    // epilogue
    float inv = 1.0f / lrow;
    float* op = out + base + (qrow0 + r) * Hn + g * 16;
    #pragma unroll
    for (int j4 = 0; j4 < 4; ++j4) {
        float4 t;
        t.x = o[j4*4+0] * inv;
        t.y = o[j4*4+1] * inv;
        t.z = o[j4*4+2] * inv;
        t.w = o[j4*4+3] * inv;
        ((float4*)op)[j4] = t;
    }
}

extern "C" void kernel_launch(void* const* d_in, const int* in_sizes, int n_in,
                              void* d_out, int out_size, void* d_ws, size_t ws_size,
                              hipStream_t stream) {
    const float* x  = (const float*)d_in[0];
    const float* Wq = (const float*)d_in[1];
    const float* Wk = (const float*)d_in[2];
    const float* Wv = (const float*)d_in[3];
    float* out = (float*)d_out;

    const size_t n = (size_t)Bn * Tn * Hn;   // 4.19M floats per tensor
    float* qws = (float*)d_ws;
    float* kws = qws + n;
    float* vws = kws + n;

    qkv_proj_kernel<<<dim3(Bn * Tn / 64), 256, 0, stream>>>(x, Wq, Wk, Wv, qws, kws, vws);
    attn_kernel<<<dim3(8, Bn), 256, 0, stream>>>(qws, kws, vws, out);
}

// Round 2
// 218.487 us; speedup vs baseline: 4.0749x; 4.0749x over previous
//
#include <hip/hip_runtime.h>
#include <hip/hip_bf16.h>
#include <math.h>

#define Bn 128
#define Tn 512
#define Cn 256
#define Hn 64
#define NQKV 192        // 3*H fused output columns
#define XP 264          // padded bf16 LDS stride (256 + 8): fragment reads conflict-free

#define CPAD 68         // fp32 padded stride for attn tiles

typedef __attribute__((ext_vector_type(8))) short short8v;   // 8 bf16 (4 VGPR)
typedef __attribute__((ext_vector_type(4))) float float4v;   // MFMA C/D

__device__ __forceinline__ ushort f2bf(float f) {
    __hip_bfloat16 h = __float2bfloat16(f);   // RNE
    return *reinterpret_cast<ushort*>(&h);
}

// ---------------------------------------------------------------------------
// Prep: WcT[m*64+h][c] = W_m[c][h] as bf16.  One block per output row (256 c).
// ---------------------------------------------------------------------------
__global__ __launch_bounds__(256) void prep_w_kernel(
    const float* __restrict__ Wq, const float* __restrict__ Wk,
    const float* __restrict__ Wv, ushort* __restrict__ wcT)
{
    const int row = blockIdx.x;          // 0..191
    const int c   = threadIdx.x;         // 0..255
    const float* W = (row < 64) ? Wq : (row < 128) ? Wk : Wv;
    const int h = row & 63;
    wcT[row * Cn + c] = f2bf(W[c * Hn + h]);
}

// ---------------------------------------------------------------------------
// QKV GEMM via MFMA: q|k|v[row][col] = sum_c x[row][c] * WcT[col][c]
// Block = 64 rows x 192 cols, 4 waves; wave w owns rows [w*16, w*16+16).
// Full WcT (192x256 bf16) + x tile (64x256 bf16) staged in LDS (135 KB).
// mfma_f32_16x16x32_bf16: A row=lane&15, k=(lane>>4)*8+j ; B col=lane&15,
// same k ; D col=lane&15, row=(lane>>4)*4+reg  [guide §3, m89-verified].
// ---------------------------------------------------------------------------
__global__ __launch_bounds__(256) void qkv_mfma_kernel(
    const float* __restrict__ x, const ushort* __restrict__ wcT,
    float* __restrict__ q, float* __restrict__ k, float* __restrict__ v)
{
    __shared__ ushort xs[64 * XP];
    __shared__ ushort wsh[NQKV * XP];
    const int tid = threadIdx.x;
    const long row0 = (long)blockIdx.x * 64;

    // stage WcT: 192*256 bf16 = 6144 x 16B chunks, 24/thread, coalesced
    {
        const uint4* w16 = (const uint4*)wcT;
        #pragma unroll
        for (int i = 0; i < 24; ++i) {
            int idx = tid + i * 256;         // 0..6143
            int r   = idx >> 5;              // 32 chunks per 256-bf16 row
            int c8  = idx & 31;
            *(uint4*)&wsh[r * XP + c8 * 8] = w16[idx];
        }
    }

    // stage x tile 64x256 fp32 -> bf16: 4096 float4, 16/thread, coalesced
    {
        const float4* x4 = (const float4*)(x + row0 * Cn);
        #pragma unroll
        for (int i = 0; i < 16; ++i) {
            int idx = tid + i * 256;         // 0..4095
            int r   = idx >> 6;              // 64 float4 per row
            int c4  = idx & 63;
            float4 f = x4[idx];
            union { ushort u[4]; uint2 p; } pk;
            pk.u[0] = f2bf(f.x); pk.u[1] = f2bf(f.y);
            pk.u[2] = f2bf(f.z); pk.u[3] = f2bf(f.w);
            *(uint2*)&xs[r * XP + c4 * 4] = pk.p;
        }
    }
    __syncthreads();

    const int lane = tid & 63;
    const int wv   = tid >> 6;        // wave 0..3
    const int lr   = lane & 15;       // A-row / B-col / D-col selector
    const int hi   = lane >> 4;       // k-group 0..3

    const ushort* arow = &xs[(wv * 16 + lr) * XP + hi * 8];
    const ushort* brow = &wsh[lr * XP + hi * 8];

    float4v acc[12];
    #pragma unroll
    for (int n = 0; n < 12; ++n) acc[n] = (float4v){0.f, 0.f, 0.f, 0.f};

    #pragma unroll
    for (int ks = 0; ks < 8; ++ks) {              // K = 256 in steps of 32
        short8v a = *(const short8v*)(arow + ks * 32);
        #pragma unroll
        for (int n = 0; n < 12; ++n) {
            short8v b = *(const short8v*)(brow + (n * 16) * XP + ks * 32);
            acc[n] = __builtin_amdgcn_mfma_f32_16x16x32_bf16(a, b, acc[n], 0, 0, 0);
        }
    }

    // epilogue: lane holds D[hi*4+reg][n*16+lr]; rows within wave's 16-strip
    const long grow0 = row0 + wv * 16 + hi * 4;
    #pragma unroll
    for (int n = 0; n < 12; ++n) {
        int col = n * 16 + lr;                    // 0..191, matrix uniform per n
        float* outp = (col < 64) ? q : (col < 128) ? k : v;
        int hcol = col & 63;
        #pragma unroll
        for (int reg = 0; reg < 4; ++reg) {
            outp[(grow0 + reg) * Hn + hcol] = acc[n][reg];
        }
    }
}

// ---------------------------------------------------------------------------
// Flash-style causal attention over q,k,v [B, T, H] fp32 — unchanged (works).
// ---------------------------------------------------------------------------
__global__ __launch_bounds__(256) void attn_kernel(
    const float* __restrict__ q, const float* __restrict__ k,
    const float* __restrict__ v, float* __restrict__ out)
{
    __shared__ float qs[64][CPAD], ks[64][CPAD], vs[64][CPAD], ps[64][CPAD];
    const int tid = threadIdx.x;
    const int qt  = blockIdx.x;    // 0..7
    const int b   = blockIdx.y;    // 0..127
    const long base  = (long)b * Tn * Hn;
    const long qrow0 = (long)qt * 64;

    {
        const float4* q4 = (const float4*)(q + base + qrow0 * Hn);
        #pragma unroll
        for (int i = 0; i < 4; ++i) {
            int idx = tid + i * 256;
            int rr  = idx >> 4;
            int c4  = idx & 15;
            *(float4*)&qs[rr][c4 * 4] = q4[idx];
        }
    }

    const int r = tid >> 2;
    const int g = tid & 3;
    float o[16];
    #pragma unroll
    for (int j = 0; j < 16; ++j) o[j] = 0.f;
    float mrow = -INFINITY, lrow = 0.f;

    for (int kt = 0; kt <= qt; ++kt) {
        __syncthreads();
        {
            const float4* k4 = (const float4*)(k + base + (long)kt * 64 * Hn);
            const float4* v4 = (const float4*)(v + base + (long)kt * 64 * Hn);
            #pragma unroll
            for (int i = 0; i < 4; ++i) {
                int idx = tid + i * 256;
                int rr  = idx >> 4;
                int c4  = idx & 15;
                *(float4*)&ks[rr][c4 * 4] = k4[idx];
                *(float4*)&vs[rr][c4 * 4] = v4[idx];
            }
        }
        __syncthreads();

        float sc[16];
        #pragma unroll
        for (int j = 0; j < 16; ++j) sc[j] = 0.f;
        for (int c4 = 0; c4 < 16; ++c4) {
            float4 qv = *(const float4*)&qs[r][c4 * 4];
            #pragma unroll
            for (int j = 0; j < 16; ++j) {
                float4 kv = *(const float4*)&ks[g + 4 * j][c4 * 4];
                sc[j] = fmaf(qv.x, kv.x, sc[j]);
                sc[j] = fmaf(qv.y, kv.y, sc[j]);
                sc[j] = fmaf(qv.z, kv.z, sc[j]);
                sc[j] = fmaf(qv.w, kv.w, sc[j]);
            }
        }

        if (kt == qt) {
            #pragma unroll
            for (int j = 0; j < 16; ++j) {
                int kc = g + 4 * j;
                sc[j] = (kc <= r) ? sc[j] * 0.125f : -INFINITY;
            }
        } else {
            #pragma unroll
            for (int j = 0; j < 16; ++j) sc[j] *= 0.125f;
        }

        float sMax = -INFINITY;
        #pragma unroll
        for (int j = 0; j < 16; ++j) sMax = fmaxf(sMax, sc[j]);
        sMax = fmaxf(sMax, __shfl_xor(sMax, 1));
        sMax = fmaxf(sMax, __shfl_xor(sMax, 2));
        float mNew  = fmaxf(mrow, sMax);
        float scale = __expf(mrow - mNew);

        float psum = 0.f;
        #pragma unroll
        for (int j = 0; j < 16; ++j) {
            float p = __expf(sc[j] - mNew);
            ps[r][g + 4 * j] = p;
            psum += p;
        }
        psum += __shfl_xor(psum, 1);
        psum += __shfl_xor(psum, 2);
        lrow = lrow * scale + psum;
        mrow = mNew;
        #pragma unroll
        for (int j = 0; j < 16; ++j) o[j] *= scale;

        for (int s = 0; s < 64; ++s) {
            float p = ps[r][s];
            #pragma unroll
            for (int j4 = 0; j4 < 4; ++j4) {
                float4 vv = *(const float4*)&vs[s][g * 16 + j4 * 4];
                o[j4*4+0] = fmaf(p, vv.x, o[j4*4+0]);
                o[j4*4+1] = fmaf(p, vv.y, o[j4*4+1]);
                o[j4*4+2] = fmaf(p, vv.z, o[j4*4+2]);
                o[j4*4+3] = fmaf(p, vv.w, o[j4*4+3]);
            }
        }
    }

    float inv = 1.0f / lrow;
    float* op = out + base + (qrow0 + r) * Hn + g * 16;
    #pragma unroll
    for (int j4 = 0; j4 < 4; ++j4) {
        float4 t;
        t.x = o[j4*4+0] * inv;
        t.y = o[j4*4+1] * inv;
        t.z = o[j4*4+2] * inv;
        t.w = o[j4*4+3] * inv;
        ((float4*)op)[j4] = t;
    }
}

extern "C" void kernel_launch(void* const* d_in, const int* in_sizes, int n_in,
                              void* d_out, int out_size, void* d_ws, size_t ws_size,
                              hipStream_t stream) {
    const float* x  = (const float*)d_in[0];
    const float* Wq = (const float*)d_in[1];
    const float* Wk = (const float*)d_in[2];
    const float* Wv = (const float*)d_in[3];
    float* out = (float*)d_out;

    const size_t n = (size_t)Bn * Tn * Hn;
    float* qws = (float*)d_ws;
    float* kws = qws + n;
    float* vws = kws + n;

    // WcT (bf16, 98 KB) lives in the head of d_out: consumed by qkv_mfma,
    // then fully overwritten by attn's epilogue (attn covers every element).
    ushort* wcT = (ushort*)d_out;

    prep_w_kernel<<<dim3(NQKV), 256, 0, stream>>>(Wq, Wk, Wv, wcT);
    qkv_mfma_kernel<<<dim3(Bn * Tn / 64), 256, 0, stream>>>(x, wcT, qws, kws, vws);
    attn_kernel<<<dim3(8, Bn), 256, 0, stream>>>(qws, kws, vws, out);
}

// Round 3
// 96.576 us; speedup vs baseline: 9.2188x; 2.2623x over previous
//
#include <hip/hip_runtime.h>
#include <hip/hip_bf16.h>
#include <math.h>

#define Bn 128
#define Tn 512
#define Cn 256
#define Hn 64
#define NQKV 192        // 3*H fused output columns
#define XP 264          // padded bf16 LDS stride for GEMM tiles
#define HP2 72          // padded bf16 LDS stride for 64-wide attn tiles (144 B)

typedef __attribute__((ext_vector_type(8))) short short8v;   // 8 bf16 (4 VGPR)
typedef __attribute__((ext_vector_type(4))) float float4v;   // MFMA C/D

__device__ __forceinline__ ushort f2bf(float f) {
    __hip_bfloat16 h = __float2bfloat16(f);   // RNE
    return *reinterpret_cast<ushort*>(&h);
}

// ---------------------------------------------------------------------------
// Prep: WcT[m*64+h][c] = W_m[c][h] as bf16.
// ---------------------------------------------------------------------------
__global__ __launch_bounds__(256) void prep_w_kernel(
    const float* __restrict__ Wq, const float* __restrict__ Wk,
    const float* __restrict__ Wv, ushort* __restrict__ wcT)
{
    const int row = blockIdx.x;          // 0..191
    const int c   = threadIdx.x;         // 0..255
    const float* W = (row < 64) ? Wq : (row < 128) ? Wk : Wv;
    const int h = row & 63;
    wcT[row * Cn + c] = f2bf(W[c * Hn + h]);
}

// ---------------------------------------------------------------------------
// QKV GEMM via MFMA, now writing bf16 q/k/v.
// ---------------------------------------------------------------------------
__global__ __launch_bounds__(256) void qkv_mfma_kernel(
    const float* __restrict__ x, const ushort* __restrict__ wcT,
    ushort* __restrict__ q, ushort* __restrict__ k, ushort* __restrict__ v)
{
    __shared__ ushort xs[64 * XP];
    __shared__ ushort wsh[NQKV * XP];
    const int tid = threadIdx.x;
    const long row0 = (long)blockIdx.x * 64;

    {
        const uint4* w16 = (const uint4*)wcT;
        #pragma unroll
        for (int i = 0; i < 24; ++i) {
            int idx = tid + i * 256;
            int r   = idx >> 5;
            int c8  = idx & 31;
            *(uint4*)&wsh[r * XP + c8 * 8] = w16[idx];
        }
    }
    {
        const float4* x4 = (const float4*)(x + row0 * Cn);
        #pragma unroll
        for (int i = 0; i < 16; ++i) {
            int idx = tid + i * 256;
            int r   = idx >> 6;
            int c4  = idx & 63;
            float4 f = x4[idx];
            union { ushort u[4]; uint2 p; } pk;
            pk.u[0] = f2bf(f.x); pk.u[1] = f2bf(f.y);
            pk.u[2] = f2bf(f.z); pk.u[3] = f2bf(f.w);
            *(uint2*)&xs[r * XP + c4 * 4] = pk.p;
        }
    }
    __syncthreads();

    const int lane = tid & 63;
    const int wv   = tid >> 6;
    const int lr   = lane & 15;
    const int hi   = lane >> 4;

    const ushort* arow = &xs[(wv * 16 + lr) * XP + hi * 8];
    const ushort* brow = &wsh[lr * XP + hi * 8];

    float4v acc[12];
    #pragma unroll
    for (int n = 0; n < 12; ++n) acc[n] = (float4v){0.f, 0.f, 0.f, 0.f};

    #pragma unroll
    for (int ks = 0; ks < 8; ++ks) {
        short8v a = *(const short8v*)(arow + ks * 32);
        #pragma unroll
        for (int n = 0; n < 12; ++n) {
            short8v b = *(const short8v*)(brow + (n * 16) * XP + ks * 32);
            acc[n] = __builtin_amdgcn_mfma_f32_16x16x32_bf16(a, b, acc[n], 0, 0, 0);
        }
    }

    const long grow0 = row0 + wv * 16 + hi * 4;
    #pragma unroll
    for (int n = 0; n < 12; ++n) {
        int col = n * 16 + lr;
        ushort* outp = (col < 64) ? q : (col < 128) ? k : v;
        int hcol = col & 63;
        #pragma unroll
        for (int reg = 0; reg < 4; ++reg) {
            outp[(grow0 + reg) * Hn + hcol] = f2bf(acc[n][reg]);
        }
    }
}

// ---------------------------------------------------------------------------
// MFMA flash attention. Block = (q-tile 64 rows, batch), 4 waves.
// Wave wv owns q-rows [wv*16, wv*16+16). Per 64-key tile:
//   QK^T: A=Qs rows, B=Ks rows (both [row][h] bf16, stride 72)  -> 8 MFMA
//   online softmax on D frags (lane holds S[hi*4+reg][n*16+lr])
//   P -> bf16 LDS (per-wave), PV: A=Pl rows, B=Vt rows (Vt=[h][s]) -> 8 MFMA
// ---------------------------------------------------------------------------
__global__ __launch_bounds__(256) void attn_mfma_kernel(
    const ushort* __restrict__ q, const ushort* __restrict__ k,
    const ushort* __restrict__ v, float* __restrict__ out)
{
    __shared__ ushort Qs[64 * HP2], Ks[64 * HP2], Vt[64 * HP2];
    __shared__ ushort Pl[4][16 * HP2];

    const int tid = threadIdx.x;
    const int qt  = blockIdx.x;    // 0..7
    const int b   = blockIdx.y;    // 0..127
    const long base = (long)b * Tn * Hn;
    const int lane = tid & 63;
    const int wv   = tid >> 6;
    const int lr   = lane & 15;
    const int hi   = lane >> 4;

    // stage Q tile: 64x64 bf16 = 512 uint4, 2 per thread, coalesced
    {
        const uint4* q4 = (const uint4*)(q + base + (long)qt * 64 * Hn);
        #pragma unroll
        for (int i = 0; i < 2; ++i) {
            int idx = tid + i * 256;      // 0..511
            int r   = idx >> 3;           // 8 uint4 per row
            int c8  = idx & 7;
            *(uint4*)&Qs[r * HP2 + c8 * 8] = q4[idx];
        }
    }

    float4v o[4];
    #pragma unroll
    for (int n = 0; n < 4; ++n) o[n] = (float4v){0.f, 0.f, 0.f, 0.f};
    float m[4], l[4];
    #pragma unroll
    for (int reg = 0; reg < 4; ++reg) { m[reg] = -INFINITY; l[reg] = 0.f; }

    const int qrow_l = wv * 16 + hi * 4;           // local q row (+reg)
    const int qrow_g0 = qt * 64 + qrow_l;          // global q row (+reg)

    for (int kt = 0; kt <= qt; ++kt) {
        __syncthreads();   // all waves done with Ks/Vt of previous tile
        // stage K tile
        {
            const uint4* k4 = (const uint4*)(k + base + (long)kt * 64 * Hn);
            #pragma unroll
            for (int i = 0; i < 2; ++i) {
                int idx = tid + i * 256;
                int r   = idx >> 3;
                int c8  = idx & 7;
                *(uint4*)&Ks[r * HP2 + c8 * 8] = k4[idx];
            }
        }
        // stage V transposed: Vt[h][s]
        {
            const uint4* v4 = (const uint4*)(v + base + (long)kt * 64 * Hn);
            #pragma unroll
            for (int i = 0; i < 2; ++i) {
                int idx = tid + i * 256;
                int s   = idx >> 3;
                int c8  = idx & 7;
                uint4 pk = v4[idx];
                const ushort* e = (const ushort*)&pk;
                #pragma unroll
                for (int t = 0; t < 8; ++t) {
                    int j = (t + c8) & 7;             // rotate: spread banks
                    Vt[(c8 * 8 + j) * HP2 + s] = e[j];
                }
            }
        }
        __syncthreads();

        // ---- QK^T ----
        float4v s4[4];
        #pragma unroll
        for (int n = 0; n < 4; ++n) s4[n] = (float4v){0.f, 0.f, 0.f, 0.f};
        const ushort* arow = &Qs[(wv * 16 + lr) * HP2 + hi * 8];
        #pragma unroll
        for (int ks = 0; ks < 2; ++ks) {
            short8v a = *(const short8v*)(arow + ks * 32);
            #pragma unroll
            for (int n = 0; n < 4; ++n) {
                short8v bb = *(const short8v*)&Ks[(n * 16 + lr) * HP2 + ks * 32 + hi * 8];
                s4[n] = __builtin_amdgcn_mfma_f32_16x16x32_bf16(a, bb, s4[n], 0, 0, 0);
            }
        }

        // ---- scale + causal mask (diag tile only) ----
        if (kt == qt) {
            #pragma unroll
            for (int n = 0; n < 4; ++n) {
                int kcol = n * 16 + lr;               // local == global offset same tile
                #pragma unroll
                for (int reg = 0; reg < 4; ++reg) {
                    float sv = s4[n][reg] * 0.125f;
                    s4[n][reg] = (kcol <= qrow_l + reg) ? sv : -INFINITY;
                }
            }
        } else {
            #pragma unroll
            for (int n = 0; n < 4; ++n)
                #pragma unroll
                for (int reg = 0; reg < 4; ++reg) s4[n][reg] *= 0.125f;
        }

        // ---- online softmax (reduce over 4 regs' n-values + 16-lane group) ----
        #pragma unroll
        for (int reg = 0; reg < 4; ++reg) {
            float mx = fmaxf(fmaxf(s4[0][reg], s4[1][reg]),
                             fmaxf(s4[2][reg], s4[3][reg]));
            mx = fmaxf(mx, __shfl_xor(mx, 1));
            mx = fmaxf(mx, __shfl_xor(mx, 2));
            mx = fmaxf(mx, __shfl_xor(mx, 4));
            mx = fmaxf(mx, __shfl_xor(mx, 8));
            float mN = fmaxf(m[reg], mx);
            float sc = __expf(m[reg] - mN);           // first tile: exp(-inf)=0
            float ps = 0.f;
            #pragma unroll
            for (int n = 0; n < 4; ++n) {
                float p = __expf(s4[n][reg] - mN);    // masked: exp(-inf)=0
                s4[n][reg] = p;
                ps += p;
            }
            ps += __shfl_xor(ps, 1);
            ps += __shfl_xor(ps, 2);
            ps += __shfl_xor(ps, 4);
            ps += __shfl_xor(ps, 8);
            l[reg] = l[reg] * sc + ps;
            m[reg] = mN;
            #pragma unroll
            for (int n = 0; n < 4; ++n) o[n][reg] *= sc;
        }

        // ---- P -> bf16 LDS (per-wave buffer; intra-wave dependency) ----
        #pragma unroll
        for (int n = 0; n < 4; ++n)
            #pragma unroll
            for (int reg = 0; reg < 4; ++reg)
                Pl[wv][(hi * 4 + reg) * HP2 + n * 16 + lr] = f2bf(s4[n][reg]);

        // ---- PV ----
        #pragma unroll
        for (int ks = 0; ks < 2; ++ks) {
            short8v a = *(const short8v*)&Pl[wv][lr * HP2 + ks * 32 + hi * 8];
            #pragma unroll
            for (int n = 0; n < 4; ++n) {
                short8v bb = *(const short8v*)&Vt[(n * 16 + lr) * HP2 + ks * 32 + hi * 8];
                o[n] = __builtin_amdgcn_mfma_f32_16x16x32_bf16(a, bb, o[n], 0, 0, 0);
            }
        }
    }

    // epilogue: out[qrow][n*16+lr] = o[n][reg] / l[reg]
    #pragma unroll
    for (int reg = 0; reg < 4; ++reg) {
        float inv = 1.0f / l[reg];
        float* orow = out + base + (long)(qrow_g0 + reg) * Hn;
        #pragma unroll
        for (int n = 0; n < 4; ++n)
            orow[n * 16 + lr] = o[n][reg] * inv;
    }
}

extern "C" void kernel_launch(void* const* d_in, const int* in_sizes, int n_in,
                              void* d_out, int out_size, void* d_ws, size_t ws_size,
                              hipStream_t stream) {
    const float* x  = (const float*)d_in[0];
    const float* Wq = (const float*)d_in[1];
    const float* Wk = (const float*)d_in[2];
    const float* Wv = (const float*)d_in[3];
    float* out = (float*)d_out;

    const size_t n = (size_t)Bn * Tn * Hn;
    ushort* qws = (ushort*)d_ws;
    ushort* kws = qws + n;
    ushort* vws = kws + n;

    // WcT (bf16, 98 KB) in d_out head: consumed by qkv_mfma, then fully
    // overwritten by attn's epilogue.
    ushort* wcT = (ushort*)d_out;

    prep_w_kernel<<<dim3(NQKV), 256, 0, stream>>>(Wq, Wk, Wv, wcT);
    qkv_mfma_kernel<<<dim3(Bn * Tn / 64), 256, 0, stream>>>(x, wcT, qws, kws, vws);
    attn_mfma_kernel<<<dim3(8, Bn), 256, 0, stream>>>(qws, kws, vws, out);
}

// Round 4
// 57.168 us; speedup vs baseline: 15.5738x; 1.6893x over previous
//
#include <hip/hip_runtime.h>
#include <hip/hip_bf16.h>
#include <math.h>

#define Bn 128
#define Tn 512
#define Cn 256
#define Hn 64
#define NQKV 192        // 3*H fused output columns
#define XP 264          // padded bf16 LDS stride for GEMM tiles
#define HP2 72          // padded bf16 LDS stride for attn tiles (144 B)
#define SCL 0.18033688011112042f   // log2(e)/8 : exp2-domain softmax scale

typedef __attribute__((ext_vector_type(8))) short short8v;   // 8 bf16
typedef __attribute__((ext_vector_type(4))) float float4v;   // MFMA C/D

__device__ __forceinline__ ushort f2bf(float f) {
    __hip_bfloat16 h = __float2bfloat16(f);   // RNE
    return *reinterpret_cast<ushort*>(&h);
}

// ---------------------------------------------------------------------------
// Prep: WcT[m*64+h][c] = W_m[c][h] as bf16.
// ---------------------------------------------------------------------------
__global__ __launch_bounds__(256) void prep_w_kernel(
    const float* __restrict__ Wq, const float* __restrict__ Wk,
    const float* __restrict__ Wv, ushort* __restrict__ wcT)
{
    const int row = blockIdx.x;          // 0..191
    const int c   = threadIdx.x;         // 0..255
    const float* W = (row < 64) ? Wq : (row < 128) ? Wk : Wv;
    const int h = row & 63;
    wcT[row * Cn + c] = f2bf(W[c * Hn + h]);
}

// ---------------------------------------------------------------------------
// QKV GEMM via MFMA. q,k written row-major bf16 [b][t][h]; v written
// TRANSPOSED vT[b][h][t] (via LDS bounce -> coalesced stores) so the attn
// kernel needs no in-kernel transpose.
// ---------------------------------------------------------------------------
__global__ __launch_bounds__(256) void qkv_mfma_kernel(
    const float* __restrict__ x, const ushort* __restrict__ wcT,
    ushort* __restrict__ q, ushort* __restrict__ k, ushort* __restrict__ vT)
{
    __shared__ ushort xs[64 * XP];
    __shared__ ushort wsh[NQKV * XP];
    const int tid = threadIdx.x;
    const long row0 = (long)blockIdx.x * 64;

    {
        const uint4* w16 = (const uint4*)wcT;
        #pragma unroll
        for (int i = 0; i < 24; ++i) {
            int idx = tid + i * 256;
            int r   = idx >> 5;
            int c8  = idx & 31;
            *(uint4*)&wsh[r * XP + c8 * 8] = w16[idx];
        }
    }
    {
        const float4* x4 = (const float4*)(x + row0 * Cn);
        #pragma unroll
        for (int i = 0; i < 16; ++i) {
            int idx = tid + i * 256;
            int r   = idx >> 6;
            int c4  = idx & 63;
            float4 f = x4[idx];
            union { ushort u[4]; uint2 p; } pk;
            pk.u[0] = f2bf(f.x); pk.u[1] = f2bf(f.y);
            pk.u[2] = f2bf(f.z); pk.u[3] = f2bf(f.w);
            *(uint2*)&xs[r * XP + c4 * 4] = pk.p;
        }
    }
    __syncthreads();

    const int lane = tid & 63;
    const int wv   = tid >> 6;
    const int lr   = lane & 15;
    const int hi   = lane >> 4;

    const ushort* arow = &xs[(wv * 16 + lr) * XP + hi * 8];
    const ushort* brow = &wsh[lr * XP + hi * 8];

    float4v acc[12];
    #pragma unroll
    for (int n = 0; n < 12; ++n) acc[n] = (float4v){0.f, 0.f, 0.f, 0.f};

    #pragma unroll
    for (int ks = 0; ks < 8; ++ks) {
        short8v a = *(const short8v*)(arow + ks * 32);
        #pragma unroll
        for (int n = 0; n < 12; ++n) {
            short8v b = *(const short8v*)(brow + (n * 16) * XP + ks * 32);
            acc[n] = __builtin_amdgcn_mfma_f32_16x16x32_bf16(a, b, acc[n], 0, 0, 0);
        }
    }

    // q,k: direct row-major stores
    const long grow0 = row0 + wv * 16 + hi * 4;
    #pragma unroll
    for (int n = 0; n < 8; ++n) {
        int col = n * 16 + lr;
        ushort* outp = (col < 64) ? q : k;
        int hcol = col & 63;
        #pragma unroll
        for (int reg = 0; reg < 4; ++reg)
            outp[(grow0 + reg) * Hn + hcol] = f2bf(acc[n][reg]);
    }

    // v: transpose via LDS (reuse xs), then coalesced store to vT[b][h][t]
    __syncthreads();                       // all waves done reading xs
    ushort* Vl = xs;                       // [64 h][stride 72] t_local
    const int tloc0 = wv * 16 + hi * 4;
    #pragma unroll
    for (int n = 8; n < 12; ++n) {
        int h = (n - 8) * 16 + lr;
        #pragma unroll
        for (int reg = 0; reg < 4; ++reg)
            Vl[h * 72 + tloc0 + reg] = f2bf(acc[n][reg]);
    }
    __syncthreads();
    {
        const int bb = (int)(row0 >> 9);         // batch
        const int t0 = (int)(row0 & 511);        // t offset within batch
        #pragma unroll
        for (int i = 0; i < 2; ++i) {
            int idx = tid + i * 256;             // 0..511
            int h   = idx >> 3;
            int c8  = idx & 7;
            *(uint4*)(vT + ((long)bb * Hn + h) * Tn + t0 + c8 * 8) =
                *(const uint4*)&Vl[h * 72 + c8 * 8];
        }
    }
}

// ---------------------------------------------------------------------------
// MFMA flash attention, 128-row Q tile, 8 waves (512 thr).
// Work-balanced 1D grid: f -> (b = (f&255)>>1, qt' = f<256 ? f&1 : 3-(f&1));
// each CU's 2 resident blocks share batch b and sum to 10 K-tiles.
// Q fragments in registers (from global). K/Vt single-buffered LDS with
// reg-staged prefetch of the next tile. Softmax in exp2 domain.
// ---------------------------------------------------------------------------
__global__ __launch_bounds__(512) void attn_mfma_kernel(
    const ushort* __restrict__ q, const ushort* __restrict__ k,
    const ushort* __restrict__ vT, float* __restrict__ out)
{
    __shared__ ushort Ks[64 * HP2];        // [key s][h]
    __shared__ ushort Vt[64 * HP2];        // [h][key s]
    __shared__ ushort Pl[8][16 * HP2];     // per-wave P rows

    const int tid = threadIdx.x;
    const int f   = blockIdx.x;            // 0..511
    const int c   = f & 255;
    const int b   = c >> 1;
    const int par = c & 1;
    const int qtp = (f < 256) ? par : (3 - par);   // q-tile 0..3
    const int ntiles = 2 * qtp + 2;

    const long base  = (long)b * Tn * Hn;  // q,k,out base
    const int lane = tid & 63;
    const int wv   = tid >> 6;             // 0..7
    const int lr   = lane & 15;
    const int hi   = lane >> 4;

    const int qrow_g = qtp * 128 + wv * 16;        // wave's first q row (global)
    const int mrow0  = qrow_g + hi * 4;            // this lane's first q row

    // Q fragments: row qrow_g+lr, k-dims [ks*32 + hi*8 ..+8)
    short8v qa[2];
    {
        const ushort* qp = q + base + (long)(qrow_g + lr) * Hn + hi * 8;
        qa[0] = *(const short8v*)(qp);
        qa[1] = *(const short8v*)(qp + 32);
    }

    // staging: 1 uint4 per thread per tensor per tile
    const int sr  = tid >> 3;              // 0..63
    const int sc8 = tid & 7;               // 0..7
    uint4 kreg = *(const uint4*)(k + base + (long)sr * Hn + sc8 * 8);               // kt=0
    uint4 vreg = *(const uint4*)(vT + base + (long)sr * Tn + sc8 * 8);              // kt=0

    float4v o[4];
    #pragma unroll
    for (int n = 0; n < 4; ++n) o[n] = (float4v){0.f, 0.f, 0.f, 0.f};
    float m[4], l[4];
    #pragma unroll
    for (int reg = 0; reg < 4; ++reg) { m[reg] = -INFINITY; l[reg] = 0.f; }

    for (int kt = 0; kt < ntiles; ++kt) {
        __syncthreads();                               // prev tile fully consumed
        *(uint4*)&Ks[sr * HP2 + sc8 * 8] = kreg;       // publish (waitcnt auto)
        *(uint4*)&Vt[sr * HP2 + sc8 * 8] = vreg;
        __syncthreads();
        if (kt + 1 < ntiles) {                         // prefetch next tile
            kreg = *(const uint4*)(k  + base + (long)((kt + 1) * 64 + sr) * Hn + sc8 * 8);
            vreg = *(const uint4*)(vT + base + (long)sr * Tn + (kt + 1) * 64 + sc8 * 8);
        }
        if (kt * 64 > qrow_g + 15) continue;           // tile fully masked for wave

        // ---- QK^T ----
        float4v s4[4];
        #pragma unroll
        for (int n = 0; n < 4; ++n) s4[n] = (float4v){0.f, 0.f, 0.f, 0.f};
        #pragma unroll
        for (int ks = 0; ks < 2; ++ks) {
            short8v a = qa[ks];
            #pragma unroll
            for (int n = 0; n < 4; ++n) {
                short8v bb = *(const short8v*)&Ks[(n * 16 + lr) * HP2 + ks * 32 + hi * 8];
                s4[n] = __builtin_amdgcn_mfma_f32_16x16x32_bf16(a, bb, s4[n], 0, 0, 0);
            }
        }

        // ---- exp2-domain scale + causal mask ----
        const bool partial = (kt * 64 + 63 > qrow_g);  // wave-uniform
        if (partial) {
            #pragma unroll
            for (int n = 0; n < 4; ++n) {
                int kcol = kt * 64 + n * 16 + lr;
                #pragma unroll
                for (int reg = 0; reg < 4; ++reg) {
                    float y = s4[n][reg] * SCL;
                    s4[n][reg] = (kcol <= mrow0 + reg) ? y : -INFINITY;
                }
            }
        } else {
            #pragma unroll
            for (int n = 0; n < 4; ++n)
                #pragma unroll
                for (int reg = 0; reg < 4; ++reg) s4[n][reg] *= SCL;
        }

        // ---- online softmax (exp2 domain; 16-lane row groups) ----
        #pragma unroll
        for (int reg = 0; reg < 4; ++reg) {
            float mx = fmaxf(fmaxf(s4[0][reg], s4[1][reg]),
                             fmaxf(s4[2][reg], s4[3][reg]));
            mx = fmaxf(mx, __shfl_xor(mx, 1));
            mx = fmaxf(mx, __shfl_xor(mx, 2));
            mx = fmaxf(mx, __shfl_xor(mx, 4));
            mx = fmaxf(mx, __shfl_xor(mx, 8));
            float mN = fmaxf(m[reg], mx);
            float sc = exp2f(m[reg] - mN);             // first tile: 0
            float ps = 0.f;
            #pragma unroll
            for (int n = 0; n < 4; ++n) {
                float p = exp2f(s4[n][reg] - mN);      // masked: 0
                s4[n][reg] = p;
                ps += p;
            }
            ps += __shfl_xor(ps, 1);
            ps += __shfl_xor(ps, 2);
            ps += __shfl_xor(ps, 4);
            ps += __shfl_xor(ps, 8);
            l[reg] = l[reg] * sc + ps;
            m[reg] = mN;
            #pragma unroll
            for (int n = 0; n < 4; ++n) o[n][reg] *= sc;
        }

        // ---- P -> bf16 LDS (intra-wave) ----
        #pragma unroll
        for (int n = 0; n < 4; ++n)
            #pragma unroll
            for (int reg = 0; reg < 4; ++reg)
                Pl[wv][(hi * 4 + reg) * HP2 + n * 16 + lr] = f2bf(s4[n][reg]);

        // ---- PV ----
        #pragma unroll
        for (int ks = 0; ks < 2; ++ks) {
            short8v a = *(const short8v*)&Pl[wv][lr * HP2 + ks * 32 + hi * 8];
            #pragma unroll
            for (int n = 0; n < 4; ++n) {
                short8v bb = *(const short8v*)&Vt[(n * 16 + lr) * HP2 + ks * 32 + hi * 8];
                o[n] = __builtin_amdgcn_mfma_f32_16x16x32_bf16(a, bb, o[n], 0, 0, 0);
            }
        }
    }

    // epilogue
    #pragma unroll
    for (int reg = 0; reg < 4; ++reg) {
        float inv = 1.0f / l[reg];
        float* orow = out + base + (long)(mrow0 + reg) * Hn;
        #pragma unroll
        for (int n = 0; n < 4; ++n)
            orow[n * 16 + lr] = o[n][reg] * inv;
    }
}

extern "C" void kernel_launch(void* const* d_in, const int* in_sizes, int n_in,
                              void* d_out, int out_size, void* d_ws, size_t ws_size,
                              hipStream_t stream) {
    const float* x  = (const float*)d_in[0];
    const float* Wq = (const float*)d_in[1];
    const float* Wk = (const float*)d_in[2];
    const float* Wv = (const float*)d_in[3];
    float* out = (float*)d_out;

    const size_t n = (size_t)Bn * Tn * Hn;
    ushort* qws = (ushort*)d_ws;
    ushort* kws = qws + n;
    ushort* vTs = kws + n;

    // WcT (bf16, 98 KB) in d_out head: consumed by qkv_mfma, then fully
    // overwritten by attn's epilogue.
    ushort* wcT = (ushort*)d_out;

    prep_w_kernel<<<dim3(NQKV), 256, 0, stream>>>(Wq, Wk, Wv, wcT);
    qkv_mfma_kernel<<<dim3(Bn * Tn / 64), 256, 0, stream>>>(x, wcT, qws, kws, vTs);
    attn_mfma_kernel<<<dim3(512), 512, 0, stream>>>(qws, kws, vTs, out);
}

// Round 5
// 54.146 us; speedup vs baseline: 16.4430x; 1.0558x over previous
//
#include <hip/hip_runtime.h>
#include <hip/hip_bf16.h>
#include <math.h>

#define Bn 128
#define Tn 512
#define Cn 256
#define Hn 64
#define NQKV 192        // 3*H fused output columns
#define HP2 72          // padded bf16 LDS stride for attn tiles (144 B)
#define SCL 0.18033688011112042f   // log2(e)/8 : exp2-domain softmax scale

typedef __attribute__((ext_vector_type(8))) short short8v;   // 8 bf16
typedef __attribute__((ext_vector_type(4))) float float4v;   // MFMA C/D

__device__ __forceinline__ ushort f2bf(float f) {
    __hip_bfloat16 h = __float2bfloat16(f);   // RNE
    return *reinterpret_cast<ushort*>(&h);
}

// ---------------------------------------------------------------------------
// Prep: WcT[m*64+h][c] = W_m[c][h] as bf16 (row-major [col][k]).
// ---------------------------------------------------------------------------
__global__ __launch_bounds__(256) void prep_w_kernel(
    const float* __restrict__ Wq, const float* __restrict__ Wk,
    const float* __restrict__ Wv, ushort* __restrict__ wcT)
{
    const int row = blockIdx.x;          // 0..191
    const int c   = threadIdx.x;         // 0..255
    const float* W = (row < 64) ? Wq : (row < 128) ? Wk : Wv;
    const int h = row & 63;
    wcT[row * Cn + c] = f2bf(W[c * Hn + h]);
}

// ---------------------------------------------------------------------------
// QKV GEMM, streaming form. Grid 256 blocks x 512 thr (8 waves), 1 block/CU.
// Block handles 256 rows = 4 chunks of 64. W-fragments live in REGISTERS
// (loaded once per block from global, L2-hot). x chunk staged in 32 KB
// XOR-swizzled LDS; next chunk's loads issued before compute (T14).
// Wave (wr=wv>>2, wc=wv&3): rows wr*32 (2 m-frags), cols wc*48 (3 n-frags).
// ---------------------------------------------------------------------------
__global__ __launch_bounds__(512, 2) void qkv_mfma_kernel(
    const float* __restrict__ x, const ushort* __restrict__ wcT,
    ushort* __restrict__ q, ushort* __restrict__ k, ushort* __restrict__ vT)
{
    __shared__ ushort xlds[64 * 256];      // 32 KB, XOR-swizzled
    __shared__ ushort Vl[64 * HP2];        // V-transpose bounce (9 KB)
    char* xb = (char*)xlds;

    const int tid  = threadIdx.x;
    const int lane = tid & 63;
    const int wv   = tid >> 6;             // 0..7
    const int lr   = lane & 15;
    const int hi   = lane >> 4;
    const int wr   = wv >> 2;              // 0..1 : 32-row strip in chunk
    const int wc   = wv & 3;               // 0..3 : 48-col strip
    const long block_row0 = (long)blockIdx.x * 256;

    // ---- B fragments: 3 n-frags x 8 ks, once per block (96 VGPR) ----
    short8v bfr[3][8];
    #pragma unroll
    for (int n = 0; n < 3; ++n) {
        const ushort* bp = wcT + (long)(wc * 48 + n * 16 + lr) * Cn + hi * 8;
        #pragma unroll
        for (int ks = 0; ks < 8; ++ks)
            bfr[n][ks] = *(const short8v*)(bp + ks * 32);
    }

    // ---- prologue: load chunk 0 (8 float4/thread, coalesced) ----
    float4 xr[8];
    {
        const float4* x4 = (const float4*)(x + block_row0 * Cn);
        #pragma unroll
        for (int i = 0; i < 8; ++i) xr[i] = x4[tid + i * 512];
    }

    for (int c = 0; c < 4; ++c) {
        // ---- cvt + swizzled ds_write of current chunk ----
        #pragma unroll
        for (int i = 0; i < 8; ++i) {
            int idx = tid + i * 512;           // 0..4095
            int r   = idx >> 6;                // 0..63
            int c4  = idx & 63;
            union { ushort u[4]; uint2 p; } pk;
            pk.u[0] = f2bf(xr[i].x); pk.u[1] = f2bf(xr[i].y);
            pk.u[2] = f2bf(xr[i].z); pk.u[3] = f2bf(xr[i].w);
            int off = (r * 512 + c4 * 8) ^ ((r & 7) << 4);
            *(uint2*)(xb + off) = pk.p;
        }
        __syncthreads();

        // ---- issue next chunk's loads (hide under compute) ----
        float4 xn[8];
        if (c < 3) {
            const float4* x4 = (const float4*)(x + (block_row0 + (c + 1) * 64) * Cn);
            #pragma unroll
            for (int i = 0; i < 8; ++i) xn[i] = x4[tid + i * 512];
        }

        // ---- compute 64x192 via MFMA ----
        float4v acc[2][3];
        #pragma unroll
        for (int s = 0; s < 2; ++s)
            #pragma unroll
            for (int n = 0; n < 3; ++n) acc[s][n] = (float4v){0.f,0.f,0.f,0.f};

        #pragma unroll
        for (int ks = 0; ks < 8; ++ks) {
            int r0 = wr * 32 + lr;
            int r1 = r0 + 16;
            short8v a0 = *(const short8v*)(xb + ((r0 * 512 + ks * 64 + hi * 16) ^ ((r0 & 7) << 4)));
            short8v a1 = *(const short8v*)(xb + ((r1 * 512 + ks * 64 + hi * 16) ^ ((r1 & 7) << 4)));
            #pragma unroll
            for (int n = 0; n < 3; ++n) {
                acc[0][n] = __builtin_amdgcn_mfma_f32_16x16x32_bf16(a0, bfr[n][ks], acc[0][n], 0, 0, 0);
                acc[1][n] = __builtin_amdgcn_mfma_f32_16x16x32_bf16(a1, bfr[n][ks], acc[1][n], 0, 0, 0);
            }
        }

        // ---- store q/k direct; V frags -> Vl bounce ----
        const long rows0 = block_row0 + c * 64;
        #pragma unroll
        for (int s = 0; s < 2; ++s) {
            #pragma unroll
            for (int n = 0; n < 3; ++n) {
                int col = wc * 48 + n * 16 + lr;
                int tl  = wr * 32 + s * 16 + hi * 4;     // local row (+reg)
                if (col < 128) {
                    ushort* outp = (col < 64) ? q : k;
                    int hcol = col & 63;
                    #pragma unroll
                    for (int reg = 0; reg < 4; ++reg)
                        outp[(rows0 + tl + reg) * Hn + hcol] = f2bf(acc[s][n][reg]);
                } else {
                    int h = col - 128;
                    #pragma unroll
                    for (int reg = 0; reg < 4; ++reg)
                        Vl[h * HP2 + tl + reg] = f2bf(acc[s][n][reg]);
                }
            }
        }
        __syncthreads();

        // ---- coalesced vT store: vT[b][h][t], 1 uint4/thread ----
        {
            const int bb = (int)(rows0 >> 9);
            const int t0 = (int)(rows0 & 511);
            int h  = tid >> 3;
            int c8 = tid & 7;
            *(uint4*)(vT + ((long)bb * Hn + h) * Tn + t0 + c8 * 8) =
                *(const uint4*)&Vl[h * HP2 + c8 * 8];
        }

        if (c < 3) {
            #pragma unroll
            for (int i = 0; i < 8; ++i) xr[i] = xn[i];
        }
    }
}

// ---------------------------------------------------------------------------
// MFMA flash attention, 128-row Q tile, 8 waves (512 thr). Unchanged (r4).
// ---------------------------------------------------------------------------
__global__ __launch_bounds__(512) void attn_mfma_kernel(
    const ushort* __restrict__ q, const ushort* __restrict__ k,
    const ushort* __restrict__ vT, float* __restrict__ out)
{
    __shared__ ushort Ks[64 * HP2];        // [key s][h]
    __shared__ ushort Vt[64 * HP2];        // [h][key s]
    __shared__ ushort Pl[8][16 * HP2];     // per-wave P rows

    const int tid = threadIdx.x;
    const int f   = blockIdx.x;            // 0..511
    const int c   = f & 255;
    const int b   = c >> 1;
    const int par = c & 1;
    const int qtp = (f < 256) ? par : (3 - par);   // q-tile 0..3
    const int ntiles = 2 * qtp + 2;

    const long base  = (long)b * Tn * Hn;
    const int lane = tid & 63;
    const int wv   = tid >> 6;             // 0..7
    const int lr   = lane & 15;
    const int hi   = lane >> 4;

    const int qrow_g = qtp * 128 + wv * 16;
    const int mrow0  = qrow_g + hi * 4;

    short8v qa[2];
    {
        const ushort* qp = q + base + (long)(qrow_g + lr) * Hn + hi * 8;
        qa[0] = *(const short8v*)(qp);
        qa[1] = *(const short8v*)(qp + 32);
    }

    const int sr  = tid >> 3;
    const int sc8 = tid & 7;
    uint4 kreg = *(const uint4*)(k + base + (long)sr * Hn + sc8 * 8);
    uint4 vreg = *(const uint4*)(vT + base + (long)sr * Tn + sc8 * 8);

    float4v o[4];
    #pragma unroll
    for (int n = 0; n < 4; ++n) o[n] = (float4v){0.f, 0.f, 0.f, 0.f};
    float m[4], l[4];
    #pragma unroll
    for (int reg = 0; reg < 4; ++reg) { m[reg] = -INFINITY; l[reg] = 0.f; }

    for (int kt = 0; kt < ntiles; ++kt) {
        __syncthreads();
        *(uint4*)&Ks[sr * HP2 + sc8 * 8] = kreg;
        *(uint4*)&Vt[sr * HP2 + sc8 * 8] = vreg;
        __syncthreads();
        if (kt + 1 < ntiles) {
            kreg = *(const uint4*)(k  + base + (long)((kt + 1) * 64 + sr) * Hn + sc8 * 8);
            vreg = *(const uint4*)(vT + base + (long)sr * Tn + (kt + 1) * 64 + sc8 * 8);
        }
        if (kt * 64 > qrow_g + 15) continue;

        float4v s4[4];
        #pragma unroll
        for (int n = 0; n < 4; ++n) s4[n] = (float4v){0.f, 0.f, 0.f, 0.f};
        #pragma unroll
        for (int ks = 0; ks < 2; ++ks) {
            short8v a = qa[ks];
            #pragma unroll
            for (int n = 0; n < 4; ++n) {
                short8v bb = *(const short8v*)&Ks[(n * 16 + lr) * HP2 + ks * 32 + hi * 8];
                s4[n] = __builtin_amdgcn_mfma_f32_16x16x32_bf16(a, bb, s4[n], 0, 0, 0);
            }
        }

        const bool partial = (kt * 64 + 63 > qrow_g);
        if (partial) {
            #pragma unroll
            for (int n = 0; n < 4; ++n) {
                int kcol = kt * 64 + n * 16 + lr;
                #pragma unroll
                for (int reg = 0; reg < 4; ++reg) {
                    float y = s4[n][reg] * SCL;
                    s4[n][reg] = (kcol <= mrow0 + reg) ? y : -INFINITY;
                }
            }
        } else {
            #pragma unroll
            for (int n = 0; n < 4; ++n)
                #pragma unroll
                for (int reg = 0; reg < 4; ++reg) s4[n][reg] *= SCL;
        }

        #pragma unroll
        for (int reg = 0; reg < 4; ++reg) {
            float mx = fmaxf(fmaxf(s4[0][reg], s4[1][reg]),
                             fmaxf(s4[2][reg], s4[3][reg]));
            mx = fmaxf(mx, __shfl_xor(mx, 1));
            mx = fmaxf(mx, __shfl_xor(mx, 2));
            mx = fmaxf(mx, __shfl_xor(mx, 4));
            mx = fmaxf(mx, __shfl_xor(mx, 8));
            float mN = fmaxf(m[reg], mx);
            float sc = exp2f(m[reg] - mN);
            float ps = 0.f;
            #pragma unroll
            for (int n = 0; n < 4; ++n) {
                float p = exp2f(s4[n][reg] - mN);
                s4[n][reg] = p;
                ps += p;
            }
            ps += __shfl_xor(ps, 1);
            ps += __shfl_xor(ps, 2);
            ps += __shfl_xor(ps, 4);
            ps += __shfl_xor(ps, 8);
            l[reg] = l[reg] * sc + ps;
            m[reg] = mN;
            #pragma unroll
            for (int n = 0; n < 4; ++n) o[n][reg] *= sc;
        }

        #pragma unroll
        for (int n = 0; n < 4; ++n)
            #pragma unroll
            for (int reg = 0; reg < 4; ++reg)
                Pl[wv][(hi * 4 + reg) * HP2 + n * 16 + lr] = f2bf(s4[n][reg]);

        #pragma unroll
        for (int ks = 0; ks < 2; ++ks) {
            short8v a = *(const short8v*)&Pl[wv][lr * HP2 + ks * 32 + hi * 8];
            #pragma unroll
            for (int n = 0; n < 4; ++n) {
                short8v bb = *(const short8v*)&Vt[(n * 16 + lr) * HP2 + ks * 32 + hi * 8];
                o[n] = __builtin_amdgcn_mfma_f32_16x16x32_bf16(a, bb, o[n], 0, 0, 0);
            }
        }
    }

    #pragma unroll
    for (int reg = 0; reg < 4; ++reg) {
        float inv = 1.0f / l[reg];
        float* orow = out + base + (long)(mrow0 + reg) * Hn;
        #pragma unroll
        for (int n = 0; n < 4; ++n)
            orow[n * 16 + lr] = o[n][reg] * inv;
    }
}

extern "C" void kernel_launch(void* const* d_in, const int* in_sizes, int n_in,
                              void* d_out, int out_size, void* d_ws, size_t ws_size,
                              hipStream_t stream) {
    const float* x  = (const float*)d_in[0];
    const float* Wq = (const float*)d_in[1];
    const float* Wk = (const float*)d_in[2];
    const float* Wv = (const float*)d_in[3];
    float* out = (float*)d_out;

    const size_t n = (size_t)Bn * Tn * Hn;
    ushort* qws = (ushort*)d_ws;
    ushort* kws = qws + n;
    ushort* vTs = kws + n;

    // WcT (bf16, 98 KB) in d_out head: consumed by qkv_mfma, then fully
    // overwritten by attn's epilogue.
    ushort* wcT = (ushort*)d_out;

    prep_w_kernel<<<dim3(NQKV), 256, 0, stream>>>(Wq, Wk, Wv, wcT);
    qkv_mfma_kernel<<<dim3(256), 512, 0, stream>>>(x, wcT, qws, kws, vTs);
    attn_mfma_kernel<<<dim3(512), 512, 0, stream>>>(qws, kws, vTs, out);
}